// Round 13
// baseline (822.544 us; speedup 1.0000x reference)
//
#include <hip/hip_runtime.h>
#include <stdint.h>

#define NN 10000
#define EE 160000
#define BB 2
#define DD 512
#define KC 1024           // xcat row: [hi(512) | lo(512)]
#define MVALID 20000
#define MPAD 20096        // 157 * 128
#define LEPS 1e-5f

typedef __bf16 bf16_t;
typedef __bf16 bf16x8 __attribute__((ext_vector_type(8)));
typedef float f32x4 __attribute__((ext_vector_type(4)));

__device__ inline void gload16(const void* g, void* l) {
  __builtin_amdgcn_global_load_lds((const __attribute__((address_space(1))) uint32_t*)g,
                                   (__attribute__((address_space(3))) uint32_t*)l,
                                   16, 0, 0);
}

// ---------------- weight convert via LDS transpose: wcat[l][n][k] = bf16(W[l][k][n]), K=512
__global__ __launch_bounds__(256) void convw_k(const float* __restrict__ Wf,
                                               const float* __restrict__ Wo,
                                               const float* __restrict__ olng,
                                               bf16_t* __restrict__ wcat) {
  __shared__ float tile[64][65];
  const int kt = blockIdx.x, nt = blockIdx.y, l = blockIdx.z;
  const float* W = (l < 3) ? (Wf + (size_t)l * 262144) : Wo;
  const int tn = threadIdx.x & 63;
  const int tk = threadIdx.x >> 6;
#pragma unroll
  for (int i = 0; i < 16; i++) {
    const int kl = tk + i * 4;
    tile[kl][tn] = W[(size_t)(kt * 64 + kl) * 512 + nt * 64 + tn];
  }
  __syncthreads();
  const int kl2 = threadIdx.x & 63;
  const int nb = threadIdx.x >> 6;
  const float gk = (l == 3) ? olng[kt * 64 + kl2] : 1.0f;
#pragma unroll
  for (int i = 0; i < 16; i++) {
    const int nl = nb + i * 4;
    bf16_t h = (bf16_t)(tile[kl2][nl] * gk);
    wcat[((size_t)l * 512 + nt * 64 + nl) * 512 + kt * 64 + kl2] = h;
  }
}

// ---------------- ub[n] = bo[n]  (then ubacc adds olnb @ Wo)
__global__ __launch_bounds__(512) void ubinit_k(const float* __restrict__ bo, float* __restrict__ ub) {
  ub[threadIdx.x] = bo[threadIdx.x];
}
__global__ __launch_bounds__(256) void ubacc_k(const float* __restrict__ olnb,
                                               const float* __restrict__ Wo,
                                               float* __restrict__ ub) {
  const int k0 = blockIdx.x * 16;
  const int tid = threadIdx.x;
#pragma unroll
  for (int h = 0; h < 2; h++) {
    const int n = tid + h * 256;
    float s = 0.f;
#pragma unroll
    for (int kk = 0; kk < 16; kk++) s += olnb[k0 + kk] * Wo[(size_t)(k0 + kk) * 512 + n];
    atomicAdd(&ub[n], s);
  }
}

// ---------------- coords + x0 hi/lo convert fused: one wave per row
__global__ __launch_bounds__(256) void coords_k(const float* __restrict__ x,
                                                const float* __restrict__ Wc,
                                                float* __restrict__ out,
                                                bf16_t* __restrict__ xcat) {
  __shared__ float smW[DD * 8];
  for (int i = threadIdx.x; i < DD * 8; i += 256) smW[i] = Wc[i];
  __syncthreads();
  const int wave = threadIdx.x >> 6, lane = threadIdx.x & 63;
  const int n = blockIdx.x * 4 + wave;
  const int b = blockIdx.y;
  const size_t row = (size_t)b * NN + n;
  const float* xr = x + row * DD + lane * 8;
  f32x4 x0 = *(const f32x4*)xr;
  f32x4 x1 = *(const f32x4*)(xr + 4);
  bf16x8 hi, lo;
#pragma unroll
  for (int j = 0; j < 8; j++) {
    float v = (j < 4) ? x0[j] : x1[j - 4];
    bf16_t h = (bf16_t)v;
    hi[j] = h;
    lo[j] = (bf16_t)(v - (float)h);
  }
  bf16_t* xc = xcat + row * KC + lane * 8;
  *(bf16x8*)xc = hi;
  *(bf16x8*)(xc + DD) = lo;
  float a[8];
#pragma unroll
  for (int dc = 0; dc < 8; dc++) a[dc] = 0.f;
#pragma unroll
  for (int j = 0; j < 8; j++) {
    float xv = (j < 4) ? x0[j] : x1[j - 4];
    const float* wrow = smW + (lane * 8 + j) * 8;
#pragma unroll
    for (int dc = 0; dc < 8; dc++) a[dc] += xv * wrow[dc];
  }
#pragma unroll
  for (int dc = 0; dc < 8; dc++)
    for (int o = 32; o >= 1; o >>= 1) a[dc] += __shfl_xor(a[dc], o);
  if (lane == 0) {
#pragma unroll
    for (int dc = 0; dc < 8; dc++) out[row * 8 + dc] = a[dc];
  }
}

// ---------------- transport (both batches, edge order) + degree count
__global__ __launch_bounds__(256) void transport_deg_k(const float* __restrict__ coords,
                                                       const int* __restrict__ srcA,
                                                       const int* __restrict__ dstA,
                                                       float* __restrict__ tr,
                                                       int* __restrict__ degc) {
  int e = blockIdx.x * 256 + threadIdx.x;
  int s = srcA[e], d = dstA[e];
#pragma unroll
  for (int b = 0; b < BB; b++) {
    const float* cs = coords + ((size_t)b * NN + s) * 8;
    const float* cd = coords + ((size_t)b * NN + d) * 8;
    float ss = 0.f;
#pragma unroll
    for (int i = 0; i < 8; i++) {
      float df = cd[i] - cs[i];
      ss += df * df;
    }
    tr[(size_t)b * EE + e] = expf(-sqrtf(ss));
  }
  atomicAdd(&degc[d], 1);
}

// ---------------- exclusive scan over N=10000 (single block)
__global__ __launch_bounds__(1024) void scan_k(const int* __restrict__ cnt, int* __restrict__ rowptr,
                                               float* __restrict__ invdeg) {
  __shared__ int part[1024];
  const int tid = threadIdx.x;
  const int CH = 10;
  int base = tid * CH;
  int local[CH];
  int s = 0;
#pragma unroll
  for (int i = 0; i < CH; i++) {
    int n = base + i;
    int c = (n < NN) ? cnt[n] : 0;
    local[i] = s;
    s += c;
  }
  part[tid] = s;
  __syncthreads();
  for (int off = 1; off < 1024; off <<= 1) {
    int v = (tid >= off) ? part[tid - off] : 0;
    __syncthreads();
    part[tid] += v;
    __syncthreads();
  }
  int excl = (tid > 0) ? part[tid - 1] : 0;
#pragma unroll
  for (int i = 0; i < CH; i++) {
    int n = base + i;
    if (n < NN) {
      rowptr[n] = excl + local[i];
      int c = cnt[n];
      invdeg[n] = 1.0f / (float)(c > 1 ? c : 1);
    }
  }
  if (tid == 0) rowptr[NN] = EE;
}

// ---------------- bucket edges by dst + write CSR-ordered payloads in one pass
__global__ __launch_bounds__(256) void fillremap_k(const int* __restrict__ srcA,
                                                   const int* __restrict__ dstA,
                                                   const int* __restrict__ rowptr,
                                                   const float* __restrict__ tr,
                                                   const float* __restrict__ invdeg,
                                                   int* __restrict__ fill,
                                                   int* __restrict__ eidA,
                                                   int* __restrict__ srcs,
                                                   float* __restrict__ trs) {
  int e = blockIdx.x * 256 + threadIdx.x;
  const int d = dstA[e];
  const int pos = rowptr[d] + atomicAdd(&fill[d], 1);
  const float idg = invdeg[d];
  eidA[pos] = e;
  srcs[pos] = srcA[e];
  trs[pos] = tr[e] * idg;
  trs[(size_t)EE + pos] = tr[(size_t)EE + e] * idg;
}

// ---------------- bf16 MFMA GEMM, K=512, bf16 out (+bias)
__global__ __launch_bounds__(256) void gemm_bt_b(const bf16_t* __restrict__ A,
                                                 const bf16_t* __restrict__ Bw,
                                                 const float* __restrict__ bias,
                                                 bf16_t* __restrict__ C, int mvalid) {
  __shared__ __align__(16) char smem[16384];
  const int tid = threadIdx.x;
  const int lane = tid & 63;
  const int wave = tid >> 6;
  const int mtile = blockIdx.x;
  const int ntile = blockIdx.y;
  const int wr = wave >> 1, wc = wave & 1;
  const int r = tid >> 2;
  const int c = tid & 3;
  const size_t aRow0 = (size_t)(mtile * 128 + r);
  const size_t bRow0 = (size_t)(ntile * 128 + r);
  char* smA = smem;
  char* smB = smem + 8192;
  char* ldsA0 = smA + tid * 16;
  char* ldsA1 = smA + 4096 + tid * 16;
  char* ldsB0 = smB + tid * 16;
  char* ldsB1 = smB + 4096 + tid * 16;

  f32x4 acc[4][4];
#pragma unroll
  for (int m = 0; m < 4; m++)
#pragma unroll
    for (int n = 0; n < 4; n++) acc[m][n] = (f32x4){0.f, 0.f, 0.f, 0.f};

  const int koff = (lane >> 4) * 16;
  const int arow = wr * 64 + (lane & 15);
  const int brow = wc * 64 + (lane & 15);

  for (int kk = 0; kk < 16; ++kk) {
    const int kbase = kk * 32 + c * 8;
    gload16(A + aRow0 * KC + kbase, ldsA0);
    gload16(A + (aRow0 + 64) * KC + kbase, ldsA1);
    gload16(Bw + bRow0 * 512 + kbase, ldsB0);
    gload16(Bw + (bRow0 + 64) * 512 + kbase, ldsB1);
    __syncthreads();
    bf16x8 af[4], bfr[4];
#pragma unroll
    for (int m = 0; m < 4; m++) af[m] = *(const bf16x8*)(smA + (arow + m * 16) * 64 + koff);
#pragma unroll
    for (int n = 0; n < 4; n++) bfr[n] = *(const bf16x8*)(smB + (brow + n * 16) * 64 + koff);
#pragma unroll
    for (int m = 0; m < 4; m++)
#pragma unroll
      for (int n = 0; n < 4; n++)
        acc[m][n] = __builtin_amdgcn_mfma_f32_16x16x32_bf16(af[m], bfr[n], acc[m][n], 0, 0, 0);
    __syncthreads();
  }

  const int crow0 = mtile * 128 + wr * 64 + (lane >> 4) * 4;
  const int ccol0 = ntile * 128 + wc * 64 + (lane & 15);
#pragma unroll
  for (int n = 0; n < 4; n++) {
    const int col = ccol0 + n * 16;
    const float bv = bias[col];
#pragma unroll
    for (int m = 0; m < 4; m++) {
      const int rw = crow0 + m * 16;
#pragma unroll
      for (int j = 0; j < 4; j++) {
        int rowi = rw + j;
        if (rowi < mvalid) C[(size_t)rowi * DD + col] = (bf16_t)(acc[m][n][j] + bv);
      }
    }
  }
}

// ---------------- bf16 MFMA GEMM, K=512, f32 out with folded out-LN epilogue
__global__ __launch_bounds__(256) void gemm_bt_f(const bf16_t* __restrict__ A,
                                                 const bf16_t* __restrict__ Bw,
                                                 const float* __restrict__ bias,
                                                 float* __restrict__ C, int mvalid,
                                                 const float* __restrict__ rs) {
  __shared__ __align__(16) char smem[16384];
  const int tid = threadIdx.x;
  const int lane = tid & 63;
  const int wave = tid >> 6;
  const int mtile = blockIdx.x;
  const int ntile = blockIdx.y;
  const int wr = wave >> 1, wc = wave & 1;
  const int r = tid >> 2;
  const int c = tid & 3;
  const size_t aRow0 = (size_t)(mtile * 128 + r);
  const size_t bRow0 = (size_t)(ntile * 128 + r);
  char* smA = smem;
  char* smB = smem + 8192;
  char* ldsA0 = smA + tid * 16;
  char* ldsA1 = smA + 4096 + tid * 16;
  char* ldsB0 = smB + tid * 16;
  char* ldsB1 = smB + 4096 + tid * 16;

  f32x4 acc[4][4];
#pragma unroll
  for (int m = 0; m < 4; m++)
#pragma unroll
    for (int n = 0; n < 4; n++) acc[m][n] = (f32x4){0.f, 0.f, 0.f, 0.f};

  const int koff = (lane >> 4) * 16;
  const int arow = wr * 64 + (lane & 15);
  const int brow = wc * 64 + (lane & 15);

  for (int kk = 0; kk < 16; ++kk) {
    const int kbase = kk * 32 + c * 8;
    gload16(A + aRow0 * KC + kbase, ldsA0);
    gload16(A + (aRow0 + 64) * KC + kbase, ldsA1);
    gload16(Bw + bRow0 * 512 + kbase, ldsB0);
    gload16(Bw + (bRow0 + 64) * 512 + kbase, ldsB1);
    __syncthreads();
    bf16x8 af[4], bfr[4];
#pragma unroll
    for (int m = 0; m < 4; m++) af[m] = *(const bf16x8*)(smA + (arow + m * 16) * 64 + koff);
#pragma unroll
    for (int n = 0; n < 4; n++) bfr[n] = *(const bf16x8*)(smB + (brow + n * 16) * 64 + koff);
#pragma unroll
    for (int m = 0; m < 4; m++)
#pragma unroll
      for (int n = 0; n < 4; n++)
        acc[m][n] = __builtin_amdgcn_mfma_f32_16x16x32_bf16(af[m], bfr[n], acc[m][n], 0, 0, 0);
    __syncthreads();
  }

  const int crow0 = mtile * 128 + wr * 64 + (lane >> 4) * 4;
  const int ccol0 = ntile * 128 + wc * 64 + (lane & 15);
#pragma unroll
  for (int n = 0; n < 4; n++) {
    const int col = ccol0 + n * 16;
    const float bv = bias[col];
#pragma unroll
    for (int m = 0; m < 4; m++) {
      const int rw = crow0 + m * 16;
#pragma unroll
      for (int j = 0; j < 4; j++) {
        int rowi = rw + j;
        if (rowi < mvalid) C[(size_t)rowi * DD + col] = acc[m][n][j] * rs[rowi] + bv;
      }
    }
  }
}

// ---------------- layer aggregation body (both batches per wave), UNROLL-deep gather pipeline
template <int FUSE_EA, int UNROLL>
__device__ inline void layer_body(int n, int lane,
                                  const bf16_t* __restrict__ xfield, int outstat,
                                  bf16_t* __restrict__ xcat,
                                  const int* __restrict__ srcs,
                                  const float* __restrict__ trs,
                                  const int* __restrict__ rowptr,
                                  const int* __restrict__ eidA,
                                  const float* __restrict__ eattr,
                                  const float* __restrict__ invdeg,
                                  float* __restrict__ eagg,
                                  const float* __restrict__ g,
                                  const float* __restrict__ bbias,
                                  float* __restrict__ rs_out) {
  const int d0 = lane * 8;
  const int beg = rowptr[n], end = rowptr[n + 1];
  const bf16_t* xf0 = xfield + (size_t)0 * NN * DD + d0;
  const bf16_t* xf1 = xfield + (size_t)1 * NN * DD + d0;
  const float* trs1p = trs + EE;
  float acc0[8], acc1[8], eac[8];
#pragma unroll
  for (int j = 0; j < 8; j++) acc0[j] = acc1[j] = eac[j] = 0.f;

  for (int c0 = beg; c0 < end; c0 += 64) {
    const int cnt = min(64, end - c0);
    int s_r = 0, e_r = 0;
    float t0_r = 0.f, t1_r = 0.f;
    if (lane < cnt) {
      s_r = srcs[c0 + lane];
      t0_r = trs[c0 + lane];
      t1_r = trs1p[c0 + lane];
      if (FUSE_EA) e_r = eidA[c0 + lane];
    }
    for (int j = 0; j < cnt; j += UNROLL) {
      // issue all UNROLL×2 gathers before consuming: deep MLP pipeline
      bf16x8 xv0[UNROLL], xv1[UNROLL];
      float t0v[UNROLL], t1v[UNROLL];
#pragma unroll
      for (int u = 0; u < UNROLL; u++) {
        const int jj = j + u;           // jj <= 63 always; lanes >= cnt carry t=0
        const int s = __shfl(s_r, jj);
        t0v[u] = __shfl(t0_r, jj);
        t1v[u] = __shfl(t1_r, jj);
        xv0[u] = *(const bf16x8*)(xf0 + (size_t)s * DD);
        xv1[u] = *(const bf16x8*)(xf1 + (size_t)s * DD);
      }
      if (FUSE_EA) {
#pragma unroll
        for (int u = 0; u < UNROLL; u++) {
          const int jj = j + u;
          const int e = __shfl(e_r, jj);
          const f32x4 r0 = __builtin_nontemporal_load((const f32x4*)(eattr + (size_t)e * DD + d0));
          const f32x4 r1 = __builtin_nontemporal_load((const f32x4*)(eattr + (size_t)e * DD + d0 + 4));
          if (jj < cnt) {
#pragma unroll
            for (int q = 0; q < 8; q++) eac[q] += (q < 4) ? r0[q & 3] : r1[q & 3];
          }
        }
      }
#pragma unroll
      for (int u = 0; u < UNROLL; u++) {
#pragma unroll
        for (int q = 0; q < 8; q++) {
          acc0[q] += t0v[u] * (float)xv0[u][q];
          acc1[q] += t1v[u] * (float)xv1[u][q];
        }
      }
    }
  }

  float ea8[8];
  if (FUSE_EA) {
    const float idg = invdeg[n];
#pragma unroll
    for (int j = 0; j < 8; j++) ea8[j] = eac[j] * idg;
    f32x4 o0, o1;
#pragma unroll
    for (int j = 0; j < 4; j++) {
      o0[j] = ea8[j];
      o1[j] = ea8[j + 4];
    }
    *(f32x4*)(eagg + (size_t)n * DD + d0) = o0;
    *(f32x4*)(eagg + (size_t)n * DD + d0 + 4) = o1;
  } else {
    const f32x4 e0 = *(const f32x4*)(eagg + (size_t)n * DD + d0);
    const f32x4 e1 = *(const f32x4*)(eagg + (size_t)n * DD + d0 + 4);
#pragma unroll
    for (int j = 0; j < 8; j++) ea8[j] = (j < 4) ? e0[j] : e1[j - 4];
  }

  bf16_t* xc0 = xcat + (size_t)n * KC + d0;
  bf16_t* xc1 = xcat + (size_t)(NN + n) * KC + d0;
  const bf16x8 h0 = *(const bf16x8*)(xc0);
  const bf16x8 l0v = *(const bf16x8*)(xc0 + DD);
  const bf16x8 h1 = *(const bf16x8*)(xc1);
  const bf16x8 l1v = *(const bf16x8*)(xc1 + DD);
  float v0[8], v1[8];
  float s10 = 0.f, s20 = 0.f, s11 = 0.f, s21 = 0.f;
#pragma unroll
  for (int j = 0; j < 8; j++) {
    const float xp0 = (float)h0[j] + (float)l0v[j];
    const float xp1 = (float)h1[j] + (float)l1v[j];
    v0[j] = xp0 + acc0[j] + ea8[j];
    v1[j] = xp1 + acc1[j] + ea8[j];
    s10 += v0[j];
    s20 += v0[j] * v0[j];
    s11 += v1[j];
    s21 += v1[j] * v1[j];
  }
#pragma unroll
  for (int o = 32; o >= 1; o >>= 1) {
    s10 += __shfl_xor(s10, o);
    s20 += __shfl_xor(s20, o);
    s11 += __shfl_xor(s11, o);
    s21 += __shfl_xor(s21, o);
  }
  const float mean0 = s10 * (1.f / 512.f);
  const float rs0 = rsqrtf(s20 * (1.f / 512.f) - mean0 * mean0 + LEPS);
  const float mean1 = s11 * (1.f / 512.f);
  const float rs1 = rsqrtf(s21 * (1.f / 512.f) - mean1 * mean1 + LEPS);
  const f32x4 g0 = *(const f32x4*)(g + d0);
  const f32x4 g1 = *(const f32x4*)(g + d0 + 4);
  const f32x4 b0 = *(const f32x4*)(bbias + d0);
  const f32x4 b1 = *(const f32x4*)(bbias + d0 + 4);
  float y0[8], y1[8];
  float sy10 = 0.f, sy20 = 0.f, sy11 = 0.f, sy21 = 0.f;
#pragma unroll
  for (int j = 0; j < 8; j++) {
    const float gg = (j < 4) ? g0[j] : g1[j - 4];
    const float bb = (j < 4) ? b0[j] : b1[j - 4];
    y0[j] = (v0[j] - mean0) * rs0 * gg + bb;
    y1[j] = (v1[j] - mean1) * rs1 * gg + bb;
    sy10 += y0[j];
    sy20 += y0[j] * y0[j];
    sy11 += y1[j];
    sy21 += y1[j] * y1[j];
  }
  float sub0 = 0.f, sub1 = 0.f;
  if (outstat) {
#pragma unroll
    for (int o = 32; o >= 1; o >>= 1) {
      sy10 += __shfl_xor(sy10, o);
      sy20 += __shfl_xor(sy20, o);
      sy11 += __shfl_xor(sy11, o);
      sy21 += __shfl_xor(sy21, o);
    }
    const float my0 = sy10 * (1.f / 512.f);
    const float rsy0 = rsqrtf(sy20 * (1.f / 512.f) - my0 * my0 + LEPS);
    const float my1 = sy11 * (1.f / 512.f);
    const float rsy1 = rsqrtf(sy21 * (1.f / 512.f) - my1 * my1 + LEPS);
    if (lane == 0) {
      rs_out[n] = rsy0;
      rs_out[NN + n] = rsy1;
    }
    sub0 = my0;
    sub1 = my1;
  }
  bf16x8 ho0, lo0, ho1, lo1;
#pragma unroll
  for (int j = 0; j < 8; j++) {
    const float ya = y0[j] - sub0;
    const float yb = y1[j] - sub1;
    bf16_t ha = (bf16_t)ya;
    bf16_t hb = (bf16_t)yb;
    ho0[j] = ha;
    lo0[j] = (bf16_t)(ya - (float)ha);
    ho1[j] = hb;
    lo1[j] = (bf16_t)(yb - (float)hb);
  }
  *(bf16x8*)xc0 = ho0;
  *(bf16x8*)xc1 = ho1;
  if (!outstat) {
    *(bf16x8*)(xc0 + DD) = lo0;
    *(bf16x8*)(xc1 + DD) = lo1;
  }
}

// ---------------- per-layer kernel (layers 0 and 1)
template <int FUSE_EA, int UNROLL>
__global__ __launch_bounds__(256) void layer_k(const bf16_t* __restrict__ xfield,
                                               bf16_t* __restrict__ xcat,
                                               const int* __restrict__ srcs,
                                               const float* __restrict__ trs,
                                               const int* __restrict__ rowptr,
                                               const int* __restrict__ eidA,
                                               const float* __restrict__ eattr,
                                               const float* __restrict__ invdeg,
                                               float* __restrict__ eagg,
                                               const float* __restrict__ g,
                                               const float* __restrict__ bbias) {
  const int wave = threadIdx.x >> 6, lane = threadIdx.x & 63;
  const int n = blockIdx.x * 4 + wave;
  layer_body<FUSE_EA, UNROLL>(n, lane, xfield, 0, xcat, srcs, trs, rowptr, eidA, eattr, invdeg,
                              eagg, g, bbias, nullptr);
}

// ---------------- tail: layer-2 blocks [0,2500) + edgemsg blocks [2500,42500) in one launch
__global__ __launch_bounds__(256) void tail_k(const bf16_t* __restrict__ xfield,
                                              bf16_t* __restrict__ xcat,
                                              const int* __restrict__ srcs,
                                              const float* __restrict__ trs,
                                              const int* __restrict__ rowptr,
                                              const float* __restrict__ eagg,
                                              const float* __restrict__ g,
                                              const float* __restrict__ bbias,
                                              float* __restrict__ rs_out,
                                              const float* __restrict__ transport,
                                              const int* __restrict__ srcA,
                                              const float* __restrict__ eattr,
                                              float* __restrict__ outE) {
  const int bid = blockIdx.x;
  const int wv = threadIdx.x >> 6, lane = threadIdx.x & 63;
  if (bid < 2500) {
    const int n = bid * 4 + wv;
    layer_body<0, 8>(n, lane, xfield, 1, xcat, srcs, trs, rowptr, nullptr, nullptr, nullptr,
                     (float*)eagg, g, bbias, rs_out);
  } else {
    const int e = (bid - 2500) * 4 + wv;
    const int d0 = lane * 8;
    const int s = srcA[e];
    const f32x4 a0 = __builtin_nontemporal_load((const f32x4*)(eattr + (size_t)e * DD + d0));
    const f32x4 a1 = __builtin_nontemporal_load((const f32x4*)(eattr + (size_t)e * DD + d0 + 4));
    const float t0 = transport[e];
    const float t1 = transport[(size_t)EE + e];
    const bf16x8 x0 = *(const bf16x8*)(xfield + (size_t)s * DD + d0);
    const bf16x8 x1 = *(const bf16x8*)(xfield + ((size_t)NN + s) * DD + d0);
    f32x4 o00, o01, o10, o11;
#pragma unroll
    for (int j = 0; j < 4; j++) {
      o00[j] = (float)x0[j] * t0 + a0[j];
      o01[j] = (float)x0[j + 4] * t0 + a1[j];
      o10[j] = (float)x1[j] * t1 + a0[j];
      o11[j] = (float)x1[j + 4] * t1 + a1[j];
    }
    float* ob0 = outE + (size_t)e * DD + d0;
    float* ob1 = outE + ((size_t)EE + e) * DD + d0;
    __builtin_nontemporal_store(o00, (f32x4*)ob0);
    __builtin_nontemporal_store(o01, (f32x4*)(ob0 + 4));
    __builtin_nontemporal_store(o10, (f32x4*)ob1);
    __builtin_nontemporal_store(o11, (f32x4*)(ob1 + 4));
  }
}

extern "C" void kernel_launch(void* const* d_in, const int* in_sizes, int n_in,
                              void* d_out, int out_size, void* d_ws, size_t ws_size,
                              hipStream_t stream) {
  const float* nf = (const float*)d_in[0];
  const int* eidx = (const int*)d_in[1];
  const float* eattr = (const float*)d_in[2];
  const float* Wc = (const float*)d_in[3];
  const float* Wf = (const float*)d_in[4];
  const float* bfield = (const float*)d_in[5];
  const float* lng = (const float*)d_in[6];
  const float* lnb = (const float*)d_in[7];
  const float* olng = (const float*)d_in[8];
  const float* olnb = (const float*)d_in[9];
  const float* Wo = (const float*)d_in[10];
  const float* bo = (const float*)d_in[11];
  const int* srcA = eidx;
  const int* dstA = eidx + EE;
  float* outp = (float*)d_out;

  char* ws = (char*)d_ws;
  size_t off = 0;
  auto alloc = [&](size_t bytes) {
    void* p = ws + off;
    off += (bytes + 255) & ~(size_t)255;
    return p;
  };
  bf16_t* xcat = (bf16_t*)alloc((size_t)MPAD * KC * 2);
  bf16_t* xfield = (bf16_t*)alloc((size_t)MPAD * DD * 2);
  bf16_t* wcat = (bf16_t*)alloc((size_t)4 * DD * 512 * 2);
  float* eagg = (float*)alloc((size_t)NN * DD * 4);
  float* coords = (float*)alloc((size_t)BB * NN * 8 * 4);
  float* transport = (float*)alloc((size_t)BB * EE * 4);
  float* trs = (float*)alloc((size_t)BB * EE * 4);
  int* srcs = (int*)alloc(EE * 4);
  int* degfill = (int*)alloc((size_t)2 * NN * 4);  // [degc | fillb], one exact memset
  int* degc = degfill;
  int* fillb = degfill + NN;
  int* rowptr = (int*)alloc((NN + 1) * 4);
  int* eidl = (int*)alloc(EE * 4);
  float* invdeg = (float*)alloc(NN * 4);
  float* rs_out = (float*)alloc((size_t)BB * NN * 4);
  float* ub = (float*)alloc(DD * 4);

  hipMemsetAsync(degfill, 0, (size_t)2 * NN * 4, stream);
  hipMemsetAsync(xcat + (size_t)MVALID * KC, 0, (size_t)(MPAD - MVALID) * KC * 2, stream);

  convw_k<<<dim3(8, 8, 4), 256, 0, stream>>>(Wf, Wo, olng, wcat);
  ubinit_k<<<1, 512, 0, stream>>>(bo, ub);
  ubacc_k<<<32, 256, 0, stream>>>(olnb, Wo, ub);
  coords_k<<<dim3(2500, 2), 256, 0, stream>>>(nf, Wc, coords, xcat);
  transport_deg_k<<<625, 256, 0, stream>>>(coords, srcA, dstA, transport, degc);
  scan_k<<<1, 1024, 0, stream>>>(degc, rowptr, invdeg);
  fillremap_k<<<625, 256, 0, stream>>>(srcA, dstA, rowptr, transport, invdeg, fillb, eidl, srcs,
                                       trs);

  for (int l = 0; l < 2; l++) {
    gemm_bt_b<<<dim3(157, 4), 256, 0, stream>>>(xcat, wcat + (size_t)l * DD * 512,
                                                bfield + l * DD, xfield, MVALID);
    if (l == 0)
      layer_k<1, 4><<<2500, 256, 0, stream>>>(xfield, xcat, srcs, trs, rowptr, eidl, eattr,
                                              invdeg, eagg, lng, lnb);
    else
      layer_k<0, 8><<<2500, 256, 0, stream>>>(xfield, xcat, srcs, trs, rowptr, eidl, eattr,
                                              invdeg, eagg, lng + DD, lnb + DD);
  }
  gemm_bt_b<<<dim3(157, 4), 256, 0, stream>>>(xcat, wcat + (size_t)2 * DD * 512, bfield + 2 * DD,
                                              xfield, MVALID);
  tail_k<<<42500, 256, 0, stream>>>(xfield, xcat, srcs, trs, rowptr, eagg, lng + 2 * DD,
                                    lnb + 2 * DD, rs_out, transport, srcA, eattr,
                                    outp + (size_t)BB * NN * DD);
  gemm_bt_f<<<dim3(157, 4), 256, 0, stream>>>(xcat, wcat + (size_t)3 * DD * 512, ub, outp, MVALID,
                                              rs_out);
}

// Round 14
// 635.423 us; speedup vs baseline: 1.2945x; 1.2945x over previous
//
#include <hip/hip_runtime.h>
#include <stdint.h>

#define NN 10000
#define EE 160000
#define BB 2
#define DD 512
#define KC 1024           // xcat row: [hi(512) | lo(512)]
#define MVALID 20000
#define MPAD 20096        // 157 * 128
#define LEPS 1e-5f

typedef __bf16 bf16_t;
typedef __bf16 bf16x8 __attribute__((ext_vector_type(8)));
typedef float f32x4 __attribute__((ext_vector_type(4)));

__device__ inline void gload16(const void* g, void* l) {
  __builtin_amdgcn_global_load_lds((const __attribute__((address_space(1))) uint32_t*)g,
                                   (__attribute__((address_space(3))) uint32_t*)l,
                                   16, 0, 0);
}

// ---------------- prologue: [0,256) convw | [256,288) ubacc | [288,5288) coords+x0 split
// all three branches are independent, read only inputs, and are resource-light (<=17KB LDS)
__global__ __launch_bounds__(256) void prologue_k(const float* __restrict__ Wf,
                                                  const float* __restrict__ Wo,
                                                  const float* __restrict__ olng,
                                                  bf16_t* __restrict__ wcat,
                                                  const float* __restrict__ olnb,
                                                  const float* __restrict__ bo,
                                                  float* __restrict__ ub,
                                                  const float* __restrict__ x,
                                                  const float* __restrict__ Wc,
                                                  float* __restrict__ coords,
                                                  bf16_t* __restrict__ xcat) {
  __shared__ __align__(16) char shmem[16896];
  const int bid = blockIdx.x;
  if (bid < 256) {
    float(*tile)[65] = (float(*)[65])shmem;  // 64*65*4 = 16640 <= 16896
    const int kt = bid & 7, nt = (bid >> 3) & 7, l = bid >> 6;
    const float* W = (l < 3) ? (Wf + (size_t)l * 262144) : Wo;
    const int tn = threadIdx.x & 63;
    const int tk = threadIdx.x >> 6;
#pragma unroll
    for (int i = 0; i < 16; i++) {
      const int kl = tk + i * 4;
      tile[kl][tn] = W[(size_t)(kt * 64 + kl) * 512 + nt * 64 + tn];
    }
    __syncthreads();
    const int kl2 = threadIdx.x & 63;
    const int nb = threadIdx.x >> 6;
    const float gk = (l == 3) ? olng[kt * 64 + kl2] : 1.0f;
#pragma unroll
    for (int i = 0; i < 16; i++) {
      const int nl = nb + i * 4;
      bf16_t h = (bf16_t)(tile[kl2][nl] * gk);
      wcat[((size_t)l * 512 + nt * 64 + nl) * 512 + kt * 64 + kl2] = h;
    }
  } else if (bid < 288) {
    const int k0 = (bid - 256) * 16;
    const int tid = threadIdx.x;
#pragma unroll
    for (int h = 0; h < 2; h++) {
      const int n = tid + h * 256;
      float s = (k0 == 0) ? bo[n] : 0.f;
#pragma unroll
      for (int kk = 0; kk < 16; kk++) s += olnb[k0 + kk] * Wo[(size_t)(k0 + kk) * 512 + n];
      atomicAdd(&ub[n], s);
    }
  } else {
    float* smW = (float*)shmem;  // 16384 bytes
    for (int i = threadIdx.x; i < DD * 8; i += 256) smW[i] = Wc[i];
    __syncthreads();
    const int v = bid - 288;
    const int wave = threadIdx.x >> 6, lane = threadIdx.x & 63;
    const int n = (v >> 1) * 4 + wave;
    const int b = v & 1;
    const size_t row = (size_t)b * NN + n;
    const float* xr = x + row * DD + lane * 8;
    f32x4 x0 = *(const f32x4*)xr;
    f32x4 x1 = *(const f32x4*)(xr + 4);
    bf16x8 hi, lo;
#pragma unroll
    for (int j = 0; j < 8; j++) {
      float vv = (j < 4) ? x0[j] : x1[j - 4];
      bf16_t h = (bf16_t)vv;
      hi[j] = h;
      lo[j] = (bf16_t)(vv - (float)h);
    }
    bf16_t* xc = xcat + row * KC + lane * 8;
    *(bf16x8*)xc = hi;
    *(bf16x8*)(xc + DD) = lo;
    float a[8];
#pragma unroll
    for (int dc = 0; dc < 8; dc++) a[dc] = 0.f;
#pragma unroll
    for (int j = 0; j < 8; j++) {
      float xv = (j < 4) ? x0[j] : x1[j - 4];
      const float* wrow = smW + (lane * 8 + j) * 8;
#pragma unroll
      for (int dc = 0; dc < 8; dc++) a[dc] += xv * wrow[dc];
    }
#pragma unroll
    for (int dc = 0; dc < 8; dc++)
      for (int o = 32; o >= 1; o >>= 1) a[dc] += __shfl_xor(a[dc], o);
    if (lane == 0) {
#pragma unroll
      for (int dc = 0; dc < 8; dc++) coords[row * 8 + dc] = a[dc];
    }
  }
}

// ---------------- transport (both batches, edge order) + degree count
__global__ __launch_bounds__(256) void transport_deg_k(const float* __restrict__ coords,
                                                       const int* __restrict__ srcA,
                                                       const int* __restrict__ dstA,
                                                       float* __restrict__ tr,
                                                       int* __restrict__ degc) {
  int e = blockIdx.x * 256 + threadIdx.x;
  int s = srcA[e], d = dstA[e];
#pragma unroll
  for (int b = 0; b < BB; b++) {
    const float* cs = coords + ((size_t)b * NN + s) * 8;
    const float* cd = coords + ((size_t)b * NN + d) * 8;
    float ss = 0.f;
#pragma unroll
    for (int i = 0; i < 8; i++) {
      float df = cd[i] - cs[i];
      ss += df * df;
    }
    tr[(size_t)b * EE + e] = expf(-sqrtf(ss));
  }
  atomicAdd(&degc[d], 1);
}

// ---------------- exclusive scan over N=10000 (single block)
__global__ __launch_bounds__(1024) void scan_k(const int* __restrict__ cnt, int* __restrict__ rowptr,
                                               float* __restrict__ invdeg) {
  __shared__ int part[1024];
  const int tid = threadIdx.x;
  const int CH = 10;
  int base = tid * CH;
  int local[CH];
  int s = 0;
#pragma unroll
  for (int i = 0; i < CH; i++) {
    int n = base + i;
    int c = (n < NN) ? cnt[n] : 0;
    local[i] = s;
    s += c;
  }
  part[tid] = s;
  __syncthreads();
  for (int off = 1; off < 1024; off <<= 1) {
    int v = (tid >= off) ? part[tid - off] : 0;
    __syncthreads();
    part[tid] += v;
    __syncthreads();
  }
  int excl = (tid > 0) ? part[tid - 1] : 0;
#pragma unroll
  for (int i = 0; i < CH; i++) {
    int n = base + i;
    if (n < NN) {
      rowptr[n] = excl + local[i];
      int c = cnt[n];
      invdeg[n] = 1.0f / (float)(c > 1 ? c : 1);
    }
  }
  if (tid == 0) rowptr[NN] = EE;
}

// ---------------- bucket edges by dst + write CSR-ordered payloads in one pass
__global__ __launch_bounds__(256) void fillremap_k(const int* __restrict__ srcA,
                                                   const int* __restrict__ dstA,
                                                   const int* __restrict__ rowptr,
                                                   const float* __restrict__ tr,
                                                   const float* __restrict__ invdeg,
                                                   int* __restrict__ fill,
                                                   int* __restrict__ eidA,
                                                   int* __restrict__ srcs,
                                                   float* __restrict__ trs) {
  int e = blockIdx.x * 256 + threadIdx.x;
  const int d = dstA[e];
  const int pos = rowptr[d] + atomicAdd(&fill[d], 1);
  const float idg = invdeg[d];
  eidA[pos] = e;
  srcs[pos] = srcA[e];
  trs[pos] = tr[e] * idg;
  trs[(size_t)EE + pos] = tr[(size_t)EE + e] * idg;
}

// ---------------- bf16 MFMA GEMM, K=512, bf16 out (+bias)
__global__ __launch_bounds__(256) void gemm_bt_b(const bf16_t* __restrict__ A,
                                                 const bf16_t* __restrict__ Bw,
                                                 const float* __restrict__ bias,
                                                 bf16_t* __restrict__ C, int mvalid) {
  __shared__ __align__(16) char smem[16384];
  const int tid = threadIdx.x;
  const int lane = tid & 63;
  const int wave = tid >> 6;
  const int mtile = blockIdx.x;
  const int ntile = blockIdx.y;
  const int wr = wave >> 1, wc = wave & 1;
  const int r = tid >> 2;
  const int c = tid & 3;
  const size_t aRow0 = (size_t)(mtile * 128 + r);
  const size_t bRow0 = (size_t)(ntile * 128 + r);
  char* smA = smem;
  char* smB = smem + 8192;
  char* ldsA0 = smA + tid * 16;
  char* ldsA1 = smA + 4096 + tid * 16;
  char* ldsB0 = smB + tid * 16;
  char* ldsB1 = smB + 4096 + tid * 16;

  f32x4 acc[4][4];
#pragma unroll
  for (int m = 0; m < 4; m++)
#pragma unroll
    for (int n = 0; n < 4; n++) acc[m][n] = (f32x4){0.f, 0.f, 0.f, 0.f};

  const int koff = (lane >> 4) * 16;
  const int arow = wr * 64 + (lane & 15);
  const int brow = wc * 64 + (lane & 15);

  for (int kk = 0; kk < 16; ++kk) {
    const int kbase = kk * 32 + c * 8;
    gload16(A + aRow0 * KC + kbase, ldsA0);
    gload16(A + (aRow0 + 64) * KC + kbase, ldsA1);
    gload16(Bw + bRow0 * 512 + kbase, ldsB0);
    gload16(Bw + (bRow0 + 64) * 512 + kbase, ldsB1);
    __syncthreads();
    bf16x8 af[4], bfr[4];
#pragma unroll
    for (int m = 0; m < 4; m++) af[m] = *(const bf16x8*)(smA + (arow + m * 16) * 64 + koff);
#pragma unroll
    for (int n = 0; n < 4; n++) bfr[n] = *(const bf16x8*)(smB + (brow + n * 16) * 64 + koff);
#pragma unroll
    for (int m = 0; m < 4; m++)
#pragma unroll
      for (int n = 0; n < 4; n++)
        acc[m][n] = __builtin_amdgcn_mfma_f32_16x16x32_bf16(af[m], bfr[n], acc[m][n], 0, 0, 0);
    __syncthreads();
  }

  const int crow0 = mtile * 128 + wr * 64 + (lane >> 4) * 4;
  const int ccol0 = ntile * 128 + wc * 64 + (lane & 15);
#pragma unroll
  for (int n = 0; n < 4; n++) {
    const int col = ccol0 + n * 16;
    const float bv = bias[col];
#pragma unroll
    for (int m = 0; m < 4; m++) {
      const int rw = crow0 + m * 16;
#pragma unroll
      for (int j = 0; j < 4; j++) {
        int rowi = rw + j;
        if (rowi < mvalid) C[(size_t)rowi * DD + col] = (bf16_t)(acc[m][n][j] + bv);
      }
    }
  }
}

// ---------------- bf16 MFMA GEMM, K=512, f32 out with folded out-LN epilogue
__global__ __launch_bounds__(256) void gemm_bt_f(const bf16_t* __restrict__ A,
                                                 const bf16_t* __restrict__ Bw,
                                                 const float* __restrict__ bias,
                                                 float* __restrict__ C, int mvalid,
                                                 const float* __restrict__ rs) {
  __shared__ __align__(16) char smem[16384];
  const int tid = threadIdx.x;
  const int lane = tid & 63;
  const int wave = tid >> 6;
  const int mtile = blockIdx.x;
  const int ntile = blockIdx.y;
  const int wr = wave >> 1, wc = wave & 1;
  const int r = tid >> 2;
  const int c = tid & 3;
  const size_t aRow0 = (size_t)(mtile * 128 + r);
  const size_t bRow0 = (size_t)(ntile * 128 + r);
  char* smA = smem;
  char* smB = smem + 8192;
  char* ldsA0 = smA + tid * 16;
  char* ldsA1 = smA + 4096 + tid * 16;
  char* ldsB0 = smB + tid * 16;
  char* ldsB1 = smB + 4096 + tid * 16;

  f32x4 acc[4][4];
#pragma unroll
  for (int m = 0; m < 4; m++)
#pragma unroll
    for (int n = 0; n < 4; n++) acc[m][n] = (f32x4){0.f, 0.f, 0.f, 0.f};

  const int koff = (lane >> 4) * 16;
  const int arow = wr * 64 + (lane & 15);
  const int brow = wc * 64 + (lane & 15);

  for (int kk = 0; kk < 16; ++kk) {
    const int kbase = kk * 32 + c * 8;
    gload16(A + aRow0 * KC + kbase, ldsA0);
    gload16(A + (aRow0 + 64) * KC + kbase, ldsA1);
    gload16(Bw + bRow0 * 512 + kbase, ldsB0);
    gload16(Bw + (bRow0 + 64) * 512 + kbase, ldsB1);
    __syncthreads();
    bf16x8 af[4], bfr[4];
#pragma unroll
    for (int m = 0; m < 4; m++) af[m] = *(const bf16x8*)(smA + (arow + m * 16) * 64 + koff);
#pragma unroll
    for (int n = 0; n < 4; n++) bfr[n] = *(const bf16x8*)(smB + (brow + n * 16) * 64 + koff);
#pragma unroll
    for (int m = 0; m < 4; m++)
#pragma unroll
      for (int n = 0; n < 4; n++)
        acc[m][n] = __builtin_amdgcn_mfma_f32_16x16x32_bf16(af[m], bfr[n], acc[m][n], 0, 0, 0);
    __syncthreads();
  }

  const int crow0 = mtile * 128 + wr * 64 + (lane >> 4) * 4;
  const int ccol0 = ntile * 128 + wc * 64 + (lane & 15);
#pragma unroll
  for (int n = 0; n < 4; n++) {
    const int col = ccol0 + n * 16;
    const float bv = bias[col];
#pragma unroll
    for (int m = 0; m < 4; m++) {
      const int rw = crow0 + m * 16;
#pragma unroll
      for (int j = 0; j < 4; j++) {
        int rowi = rw + j;
        if (rowi < mvalid) C[(size_t)rowi * DD + col] = acc[m][n][j] * rs[rowi] + bv;
      }
    }
  }
}

// ---------------- layer aggregation body (both batches per wave), R10 consume-immediately unroll 4
template <int FUSE_EA>
__device__ inline void layer_body(int n, int lane,
                                  const bf16_t* __restrict__ xfield, int outstat,
                                  bf16_t* __restrict__ xcat,
                                  const int* __restrict__ srcs,
                                  const float* __restrict__ trs,
                                  const int* __restrict__ rowptr,
                                  const int* __restrict__ eidA,
                                  const float* __restrict__ eattr,
                                  const float* __restrict__ invdeg,
                                  float* __restrict__ eagg,
                                  const float* __restrict__ g,
                                  const float* __restrict__ bbias,
                                  float* __restrict__ rs_out) {
  const int d0 = lane * 8;
  const int beg = rowptr[n], end = rowptr[n + 1];
  const bf16_t* xf0 = xfield + (size_t)0 * NN * DD + d0;
  const bf16_t* xf1 = xfield + (size_t)1 * NN * DD + d0;
  const float* trs1p = trs + EE;
  float acc0[8], acc1[8], eac[8];
#pragma unroll
  for (int j = 0; j < 8; j++) acc0[j] = acc1[j] = eac[j] = 0.f;

  for (int c0 = beg; c0 < end; c0 += 64) {
    const int cnt = min(64, end - c0);
    int s_r = 0, e_r = 0;
    float t0_r = 0.f, t1_r = 0.f;
    if (lane < cnt) {
      s_r = srcs[c0 + lane];
      t0_r = trs[c0 + lane];
      t1_r = trs1p[c0 + lane];
      if (FUSE_EA) e_r = eidA[c0 + lane];
    }
    for (int j = 0; j < cnt; j += 4) {
#pragma unroll
      for (int u = 0; u < 4; u++) {
        const int jj = j + u;
        const int s = __shfl(s_r, jj);
        const float t0 = __shfl(t0_r, jj);
        const float t1 = __shfl(t1_r, jj);
        const bf16x8 xv0 = *(const bf16x8*)(xf0 + (size_t)s * DD);
        const bf16x8 xv1 = *(const bf16x8*)(xf1 + (size_t)s * DD);
        if (FUSE_EA) {
          const int e = __shfl(e_r, jj);
          const bool act = jj < cnt;
          const f32x4 r0 = __builtin_nontemporal_load((const f32x4*)(eattr + (size_t)e * DD + d0));
          const f32x4 r1 = __builtin_nontemporal_load((const f32x4*)(eattr + (size_t)e * DD + d0 + 4));
          if (act) {
#pragma unroll
            for (int q = 0; q < 8; q++) eac[q] += (q < 4) ? r0[q & 3] : r1[q & 3];
          }
        }
#pragma unroll
        for (int q = 0; q < 8; q++) {
          acc0[q] += t0 * (float)xv0[q];
          acc1[q] += t1 * (float)xv1[q];
        }
      }
    }
  }

  float ea8[8];
  if (FUSE_EA) {
    const float idg = invdeg[n];
#pragma unroll
    for (int j = 0; j < 8; j++) ea8[j] = eac[j] * idg;
    f32x4 o0, o1;
#pragma unroll
    for (int j = 0; j < 4; j++) {
      o0[j] = ea8[j];
      o1[j] = ea8[j + 4];
    }
    *(f32x4*)(eagg + (size_t)n * DD + d0) = o0;
    *(f32x4*)(eagg + (size_t)n * DD + d0 + 4) = o1;
  } else {
    const f32x4 e0 = *(const f32x4*)(eagg + (size_t)n * DD + d0);
    const f32x4 e1 = *(const f32x4*)(eagg + (size_t)n * DD + d0 + 4);
#pragma unroll
    for (int j = 0; j < 8; j++) ea8[j] = (j < 4) ? e0[j] : e1[j - 4];
  }

  bf16_t* xc0 = xcat + (size_t)n * KC + d0;
  bf16_t* xc1 = xcat + (size_t)(NN + n) * KC + d0;
  const bf16x8 h0 = *(const bf16x8*)(xc0);
  const bf16x8 l0v = *(const bf16x8*)(xc0 + DD);
  const bf16x8 h1 = *(const bf16x8*)(xc1);
  const bf16x8 l1v = *(const bf16x8*)(xc1 + DD);
  float v0[8], v1[8];
  float s10 = 0.f, s20 = 0.f, s11 = 0.f, s21 = 0.f;
#pragma unroll
  for (int j = 0; j < 8; j++) {
    const float xp0 = (float)h0[j] + (float)l0v[j];
    const float xp1 = (float)h1[j] + (float)l1v[j];
    v0[j] = xp0 + acc0[j] + ea8[j];
    v1[j] = xp1 + acc1[j] + ea8[j];
    s10 += v0[j];
    s20 += v0[j] * v0[j];
    s11 += v1[j];
    s21 += v1[j] * v1[j];
  }
#pragma unroll
  for (int o = 32; o >= 1; o >>= 1) {
    s10 += __shfl_xor(s10, o);
    s20 += __shfl_xor(s20, o);
    s11 += __shfl_xor(s11, o);
    s21 += __shfl_xor(s21, o);
  }
  const float mean0 = s10 * (1.f / 512.f);
  const float rs0 = rsqrtf(s20 * (1.f / 512.f) - mean0 * mean0 + LEPS);
  const float mean1 = s11 * (1.f / 512.f);
  const float rs1 = rsqrtf(s21 * (1.f / 512.f) - mean1 * mean1 + LEPS);
  const f32x4 g0 = *(const f32x4*)(g + d0);
  const f32x4 g1 = *(const f32x4*)(g + d0 + 4);
  const f32x4 b0 = *(const f32x4*)(bbias + d0);
  const f32x4 b1 = *(const f32x4*)(bbias + d0 + 4);
  float y0[8], y1[8];
  float sy10 = 0.f, sy20 = 0.f, sy11 = 0.f, sy21 = 0.f;
#pragma unroll
  for (int j = 0; j < 8; j++) {
    const float gg = (j < 4) ? g0[j] : g1[j - 4];
    const float bb = (j < 4) ? b0[j] : b1[j - 4];
    y0[j] = (v0[j] - mean0) * rs0 * gg + bb;
    y1[j] = (v1[j] - mean1) * rs1 * gg + bb;
    sy10 += y0[j];
    sy20 += y0[j] * y0[j];
    sy11 += y1[j];
    sy21 += y1[j] * y1[j];
  }
  float sub0 = 0.f, sub1 = 0.f;
  if (outstat) {
#pragma unroll
    for (int o = 32; o >= 1; o >>= 1) {
      sy10 += __shfl_xor(sy10, o);
      sy20 += __shfl_xor(sy20, o);
      sy11 += __shfl_xor(sy11, o);
      sy21 += __shfl_xor(sy21, o);
    }
    const float my0 = sy10 * (1.f / 512.f);
    const float rsy0 = rsqrtf(sy20 * (1.f / 512.f) - my0 * my0 + LEPS);
    const float my1 = sy11 * (1.f / 512.f);
    const float rsy1 = rsqrtf(sy21 * (1.f / 512.f) - my1 * my1 + LEPS);
    if (lane == 0) {
      rs_out[n] = rsy0;
      rs_out[NN + n] = rsy1;
    }
    sub0 = my0;
    sub1 = my1;
  }
  bf16x8 ho0, lo0, ho1, lo1;
#pragma unroll
  for (int j = 0; j < 8; j++) {
    const float ya = y0[j] - sub0;
    const float yb = y1[j] - sub1;
    bf16_t ha = (bf16_t)ya;
    bf16_t hb = (bf16_t)yb;
    ho0[j] = ha;
    lo0[j] = (bf16_t)(ya - (float)ha);
    ho1[j] = hb;
    lo1[j] = (bf16_t)(yb - (float)hb);
  }
  *(bf16x8*)xc0 = ho0;
  *(bf16x8*)xc1 = ho1;
  if (!outstat) {
    *(bf16x8*)(xc0 + DD) = lo0;
    *(bf16x8*)(xc1 + DD) = lo1;
  }
}

// ---------------- per-layer kernel (layers 0 and 1)
template <int FUSE_EA>
__global__ __launch_bounds__(256) void layer_k(const bf16_t* __restrict__ xfield,
                                               bf16_t* __restrict__ xcat,
                                               const int* __restrict__ srcs,
                                               const float* __restrict__ trs,
                                               const int* __restrict__ rowptr,
                                               const int* __restrict__ eidA,
                                               const float* __restrict__ eattr,
                                               const float* __restrict__ invdeg,
                                               float* __restrict__ eagg,
                                               const float* __restrict__ g,
                                               const float* __restrict__ bbias) {
  const int wave = threadIdx.x >> 6, lane = threadIdx.x & 63;
  const int n = blockIdx.x * 4 + wave;
  layer_body<FUSE_EA>(n, lane, xfield, 0, xcat, srcs, trs, rowptr, eidA, eattr, invdeg, eagg, g,
                      bbias, nullptr);
}

// ---------------- tail: layer-2 blocks [0,2500) + edgemsg blocks [2500,42500) in one launch
__global__ __launch_bounds__(256) void tail_k(const bf16_t* __restrict__ xfield,
                                              bf16_t* __restrict__ xcat,
                                              const int* __restrict__ srcs,
                                              const float* __restrict__ trs,
                                              const int* __restrict__ rowptr,
                                              const float* __restrict__ eagg,
                                              const float* __restrict__ g,
                                              const float* __restrict__ bbias,
                                              float* __restrict__ rs_out,
                                              const float* __restrict__ transport,
                                              const int* __restrict__ srcA,
                                              const float* __restrict__ eattr,
                                              float* __restrict__ outE) {
  const int bid = blockIdx.x;
  const int wv = threadIdx.x >> 6, lane = threadIdx.x & 63;
  if (bid < 2500) {
    const int n = bid * 4 + wv;
    layer_body<0>(n, lane, xfield, 1, xcat, srcs, trs, rowptr, nullptr, nullptr, nullptr,
                  (float*)eagg, g, bbias, rs_out);
  } else {
    const int e = (bid - 2500) * 4 + wv;
    const int d0 = lane * 8;
    const int s = srcA[e];
    const f32x4 a0 = __builtin_nontemporal_load((const f32x4*)(eattr + (size_t)e * DD + d0));
    const f32x4 a1 = __builtin_nontemporal_load((const f32x4*)(eattr + (size_t)e * DD + d0 + 4));
    const float t0 = transport[e];
    const float t1 = transport[(size_t)EE + e];
    const bf16x8 x0 = *(const bf16x8*)(xfield + (size_t)s * DD + d0);
    const bf16x8 x1 = *(const bf16x8*)(xfield + ((size_t)NN + s) * DD + d0);
    f32x4 o00, o01, o10, o11;
#pragma unroll
    for (int j = 0; j < 4; j++) {
      o00[j] = (float)x0[j] * t0 + a0[j];
      o01[j] = (float)x0[j + 4] * t0 + a1[j];
      o10[j] = (float)x1[j] * t1 + a0[j];
      o11[j] = (float)x1[j + 4] * t1 + a1[j];
    }
    float* ob0 = outE + (size_t)e * DD + d0;
    float* ob1 = outE + ((size_t)EE + e) * DD + d0;
    __builtin_nontemporal_store(o00, (f32x4*)ob0);
    __builtin_nontemporal_store(o01, (f32x4*)(ob0 + 4));
    __builtin_nontemporal_store(o10, (f32x4*)ob1);
    __builtin_nontemporal_store(o11, (f32x4*)(ob1 + 4));
  }
}

extern "C" void kernel_launch(void* const* d_in, const int* in_sizes, int n_in,
                              void* d_out, int out_size, void* d_ws, size_t ws_size,
                              hipStream_t stream) {
  const float* nf = (const float*)d_in[0];
  const int* eidx = (const int*)d_in[1];
  const float* eattr = (const float*)d_in[2];
  const float* Wc = (const float*)d_in[3];
  const float* Wf = (const float*)d_in[4];
  const float* bfield = (const float*)d_in[5];
  const float* lng = (const float*)d_in[6];
  const float* lnb = (const float*)d_in[7];
  const float* olng = (const float*)d_in[8];
  const float* olnb = (const float*)d_in[9];
  const float* Wo = (const float*)d_in[10];
  const float* bo = (const float*)d_in[11];
  const int* srcA = eidx;
  const int* dstA = eidx + EE;
  float* outp = (float*)d_out;

  char* ws = (char*)d_ws;
  size_t off = 0;
  auto alloc = [&](size_t bytes) {
    void* p = ws + off;
    off += (bytes + 255) & ~(size_t)255;
    return p;
  };
  bf16_t* xcat = (bf16_t*)alloc((size_t)MPAD * KC * 2);
  bf16_t* xfield = (bf16_t*)alloc((size_t)MPAD * DD * 2);
  bf16_t* wcat = (bf16_t*)alloc((size_t)4 * DD * 512 * 2);
  float* eagg = (float*)alloc((size_t)NN * DD * 4);
  float* coords = (float*)alloc((size_t)BB * NN * 8 * 4);
  float* transport = (float*)alloc((size_t)BB * EE * 4);
  float* trs = (float*)alloc((size_t)BB * EE * 4);
  int* srcs = (int*)alloc(EE * 4);
  // [degc | fillb | ub] in one block, one exact memset
  char* zblk = (char*)alloc((size_t)2 * NN * 4 + DD * 4);
  int* degc = (int*)zblk;
  int* fillb = degc + NN;
  float* ub = (float*)(zblk + (size_t)2 * NN * 4);
  int* rowptr = (int*)alloc((NN + 1) * 4);
  int* eidl = (int*)alloc(EE * 4);
  float* invdeg = (float*)alloc(NN * 4);
  float* rs_out = (float*)alloc((size_t)BB * NN * 4);

  hipMemsetAsync(zblk, 0, (size_t)2 * NN * 4 + DD * 4, stream);
  hipMemsetAsync(xcat + (size_t)MVALID * KC, 0, (size_t)(MPAD - MVALID) * KC * 2, stream);

  prologue_k<<<5288, 256, 0, stream>>>(Wf, Wo, olng, wcat, olnb, bo, ub, nf, Wc, coords, xcat);
  transport_deg_k<<<625, 256, 0, stream>>>(coords, srcA, dstA, transport, degc);
  scan_k<<<1, 1024, 0, stream>>>(degc, rowptr, invdeg);
  fillremap_k<<<625, 256, 0, stream>>>(srcA, dstA, rowptr, transport, invdeg, fillb, eidl, srcs,
                                       trs);

  for (int l = 0; l < 2; l++) {
    gemm_bt_b<<<dim3(157, 4), 256, 0, stream>>>(xcat, wcat + (size_t)l * DD * 512,
                                                bfield + l * DD, xfield, MVALID);
    if (l == 0)
      layer_k<1><<<2500, 256, 0, stream>>>(xfield, xcat, srcs, trs, rowptr, eidl, eattr, invdeg,
                                           eagg, lng, lnb);
    else
      layer_k<0><<<2500, 256, 0, stream>>>(xfield, xcat, srcs, trs, rowptr, eidl, eattr, invdeg,
                                           eagg, lng + DD, lnb + DD);
  }
  gemm_bt_b<<<dim3(157, 4), 256, 0, stream>>>(xcat, wcat + (size_t)2 * DD * 512, bfield + 2 * DD,
                                              xfield, MVALID);
  tail_k<<<42500, 256, 0, stream>>>(xfield, xcat, srcs, trs, rowptr, eagg, lng + 2 * DD,
                                    lnb + 2 * DD, rs_out, transport, srcA, eattr,
                                    outp + (size_t)BB * NN * DD);
  gemm_bt_f<<<dim3(157, 4), 256, 0, stream>>>(xcat, wcat + (size_t)3 * DD * 512, ub, outp, MVALID,
                                              rs_out);
}